// Round 3
// baseline (386.513 us; speedup 1.0000x reference)
//
#include <hip/hip_runtime.h>

// Quaternion max-amplitude 2x2 pool.
// x: (16, 256, 128, 128) fp32 -> out: (16, 256, 64, 64) fp32
// channels = 4 quaternion components x 64.
// For each (b, c4, oh, ow): amp2[kk] = sum_q x[b, q*64+c4, 2oh+kh, 2ow+kw]^2,
// kk = kh*2+kw; pick first argmax kk (strict > scan, matches jnp.argmax);
// emit all 4 components at that kk.
//
// R2: same as R1 but with clang ext_vector_type for the nontemporal builtins
// (HIP_vector_type float4 is a struct and is rejected by the builtin).
// 4 output columns per thread, 16 independent 16B loads, dwordx4 stores.

#define IN_H 128
#define IN_W 128
#define C4   64
#define OUT_H 64
#define OUT_W 64

typedef float vfloat4 __attribute__((ext_vector_type(4)));

__device__ __forceinline__ vfloat4 nt_load4(const float* p) {
    return __builtin_nontemporal_load((const vfloat4*)p);
}
__device__ __forceinline__ void nt_store4(float* p, vfloat4 v) {
    __builtin_nontemporal_store(v, (vfloat4*)p);
}

__global__ __launch_bounds__(256, 4) void qpool_kernel(const float* __restrict__ x,
                                                       float* __restrict__ out) {
    // total threads = 16 * 64 * 64 * 16 = 1048576
    // each thread handles 4 adjacent output columns (8 input columns)
    int tid = blockIdx.x * blockDim.x + threadIdx.x;
    int ow4 = tid & 15;          // covers out cols 4*ow4 .. 4*ow4+3
    int oh  = (tid >> 4) & 63;
    int c4i = (tid >> 10) & 63;
    int b   = tid >> 16;

    const long in_ch_stride = (long)IN_H * IN_W;        // 16384
    const long in_b_stride  = 256L * in_ch_stride;
    const float* base = x + (long)b * in_b_stride + (long)c4i * in_ch_stride
                          + (long)(2 * oh) * IN_W + 8 * ow4;

    // arr[q][kh][col]  col in 0..7 (input columns 8*ow4 .. 8*ow4+7)
    float arr[4][2][8];
    #pragma unroll
    for (int q = 0; q < 4; ++q) {
        const float* p = base + (long)q * C4 * in_ch_stride;
        vfloat4 r0a = nt_load4(p);
        vfloat4 r0b = nt_load4(p + 4);
        vfloat4 r1a = nt_load4(p + IN_W);
        vfloat4 r1b = nt_load4(p + IN_W + 4);
        #pragma unroll
        for (int i = 0; i < 4; ++i) {
            arr[q][0][i]     = r0a[i];
            arr[q][0][4 + i] = r0b[i];
            arr[q][1][i]     = r1a[i];
            arr[q][1][4 + i] = r1b[i];
        }
    }

    float res[4][4];  // [q][slot]
    #pragma unroll
    for (int s = 0; s < 4; ++s) {
        // window columns for this output slot: 2*s + kw
        float amp[4];
        #pragma unroll
        for (int kk = 0; kk < 4; ++kk) {
            const int kh = kk >> 1, kw = kk & 1;
            float sum = 0.f;
            #pragma unroll
            for (int q = 0; q < 4; ++q) {
                float t = arr[q][kh][2 * s + kw];
                sum += t * t;
            }
            amp[kk] = sum;
        }
        // first-occurrence argmax (strict >): matches jnp.argmax
        int best = 0;
        float bv = amp[0];
        #pragma unroll
        for (int kk = 1; kk < 4; ++kk) {
            if (amp[kk] > bv) { bv = amp[kk]; best = kk; }
        }
        #pragma unroll
        for (int q = 0; q < 4; ++q) {
            float r = arr[q][0][2 * s + 0];
            r = (best == 1) ? arr[q][0][2 * s + 1] : r;
            r = (best == 2) ? arr[q][1][2 * s + 0] : r;
            r = (best == 3) ? arr[q][1][2 * s + 1] : r;
            res[q][s] = r;
        }
    }

    const long out_ch_stride = (long)OUT_H * OUT_W;     // 4096
    const long out_b_stride  = 256L * out_ch_stride;
    float* obase = out + (long)b * out_b_stride + (long)c4i * out_ch_stride
                       + (long)oh * OUT_W + 4 * ow4;
    #pragma unroll
    for (int q = 0; q < 4; ++q) {
        vfloat4 w;
        w[0] = res[q][0];
        w[1] = res[q][1];
        w[2] = res[q][2];
        w[3] = res[q][3];
        nt_store4(obase + (long)q * C4 * out_ch_stride, w);
    }
}

extern "C" void kernel_launch(void* const* d_in, const int* in_sizes, int n_in,
                              void* d_out, int out_size, void* d_ws, size_t ws_size,
                              hipStream_t stream) {
    const float* x = (const float*)d_in[0];
    float* out = (float*)d_out;
    // threads: 16 * 64 * 64 * 16 = 1048576; blocks = 4096
    const int total = 16 * 64 * 64 * 16;
    const int block = 256;
    const int grid = total / block;
    qpool_kernel<<<grid, block, 0, stream>>>(x, out);
}

// Round 4
// 374.291 us; speedup vs baseline: 1.0327x; 1.0327x over previous
//
#include <hip/hip_runtime.h>

// Quaternion max-amplitude 2x2 pool.
// x: (16, 256, 128, 128) fp32 -> out: (16, 256, 64, 64) fp32
// channels = 4 quaternion components x 64.
// For each (b, c4, oh, ow): amp2[kk] = sum_q x[b, q*64+c4, 2oh+kh, 2ow+kw]^2,
// kk = kh*2+kw; pick first argmax kk (strict > scan, matches jnp.argmax);
// emit all 4 components at that kk.
//
// R4: back to R0's dense per-lane float4 pattern (R2's strided pairs + NT
// regressed). New: persistent waves — each thread handles 8 tiles via a
// grid-stride loop whose stride only advances the batch index (+2*in_b per
// iter, constant pointer increment). unroll 2 so next iter's loads overlap
// current iter's compute. 256K threads, 1024 blocks.

#define IN_H 128
#define IN_W 128
#define C4   64
#define OUT_H 64
#define OUT_W 64
#define ITERS 8

__global__ __launch_bounds__(256, 4) void qpool_kernel(const float* __restrict__ x,
                                                       float* __restrict__ out) {
    // logical tiles: 16*64*64*32 = 2097152; threads = 2^18 = 262144
    // tid bits: ow2[0:4] oh[5:10] c4i[11:16] b0[17]
    int tid = blockIdx.x * blockDim.x + threadIdx.x;
    int ow2 = tid & 31;          // float4 group: covers ow = 2*ow2, 2*ow2+1
    int oh  = (tid >> 5) & 63;
    int c4i = (tid >> 11) & 63;
    int b0  = tid >> 17;         // 0..1; iter i handles b = b0 + 2*i

    const long in_ch_stride = (long)IN_H * IN_W;        // 16384
    const long in_b_stride  = 256L * in_ch_stride;
    const long out_ch_stride = (long)OUT_H * OUT_W;     // 4096
    const long out_b_stride  = 256L * out_ch_stride;

    const float* p0 = x + (long)b0 * in_b_stride + (long)c4i * in_ch_stride
                        + (long)(2 * oh) * IN_W + 4 * ow2;
    float* o0 = out + (long)b0 * out_b_stride + (long)c4i * out_ch_stride
                    + (long)oh * OUT_W + 2 * ow2;

    #pragma unroll 2
    for (int it = 0; it < ITERS; ++it) {
        const float* base = p0 + (long)it * 2 * in_b_stride;
        float* obase = o0 + (long)it * 2 * out_b_stride;

        // arr[q][kh][col]  col in 0..3 (input columns 4*ow2 .. 4*ow2+3)
        float arr[4][2][4];
        #pragma unroll
        for (int q = 0; q < 4; ++q) {
            const float* p = base + (long)q * C4 * in_ch_stride;
            float4 r0 = *(const float4*)(p);
            float4 r1 = *(const float4*)(p + IN_W);
            arr[q][0][0] = r0.x; arr[q][0][1] = r0.y; arr[q][0][2] = r0.z; arr[q][0][3] = r0.w;
            arr[q][1][0] = r1.x; arr[q][1][1] = r1.y; arr[q][1][2] = r1.z; arr[q][1][3] = r1.w;
        }

        float res[4][2];  // [q][slot]
        #pragma unroll
        for (int s = 0; s < 2; ++s) {
            float amp[4];
            #pragma unroll
            for (int kk = 0; kk < 4; ++kk) {
                const int kh = kk >> 1, kw = kk & 1;
                float sum = 0.f;
                #pragma unroll
                for (int q = 0; q < 4; ++q) {
                    float t = arr[q][kh][2 * s + kw];
                    sum += t * t;
                }
                amp[kk] = sum;
            }
            // first-occurrence argmax (strict >): matches jnp.argmax
            int best = 0;
            float bv = amp[0];
            #pragma unroll
            for (int kk = 1; kk < 4; ++kk) {
                if (amp[kk] > bv) { bv = amp[kk]; best = kk; }
            }
            #pragma unroll
            for (int q = 0; q < 4; ++q) {
                float r = arr[q][0][2 * s + 0];
                r = (best == 1) ? arr[q][0][2 * s + 1] : r;
                r = (best == 2) ? arr[q][1][2 * s + 0] : r;
                r = (best == 3) ? arr[q][1][2 * s + 1] : r;
                res[q][s] = r;
            }
        }

        #pragma unroll
        for (int q = 0; q < 4; ++q) {
            float2 w;
            w.x = res[q][0];
            w.y = res[q][1];
            *(float2*)(obase + (long)q * C4 * out_ch_stride) = w;
        }
    }
}

extern "C" void kernel_launch(void* const* d_in, const int* in_sizes, int n_in,
                              void* d_out, int out_size, void* d_ws, size_t ws_size,
                              hipStream_t stream) {
    const float* x = (const float*)d_in[0];
    float* out = (float*)d_out;
    // threads: 2^18 = 262144; blocks = 1024; 8 tiles per thread
    const int total_threads = 262144;
    const int block = 256;
    const int grid = total_threads / block;
    qpool_kernel<<<grid, block, 0, stream>>>(x, out);
}

// Round 5
// 366.565 us; speedup vs baseline: 1.0544x; 1.0211x over previous
//
#include <hip/hip_runtime.h>

// Quaternion max-amplitude 2x2 pool.
// x: (16, 256, 128, 128) fp32 -> out: (16, 256, 64, 64) fp32
// channels = 4 quaternion components x 64.
// For each (b, c4, oh, ow): amp2[kk] = sum_q x[b, q*64+c4, 2oh+kh, 2ow+kw]^2,
// kk = kh*2+kw; pick first argmax kk (strict > scan, matches jnp.argmax);
// emit all 4 components at that kk.
//
// R5 = exact R0 revert (best measured: 365.7 us total).
// Why R0 wins: per wave, the two float4 loads per q cover a contiguous 2 KB
// input span ([rows 2oh..2oh+3] x 512 B) in full 512 B segments; stores are
// one contiguous 512 B segment per q. Kernel-side traffic 320 MB ~= 51 us at
// 6.3 TB/s; measured total is consistent with kernel-at-floor + harness
// restore/poison (~310 us). R2 (NT + strided 4-col) and R4 (persistent waves)
// both regressed -> structural changes only add overhead at the floor.

#define IN_H 128
#define IN_W 128
#define C4   64
#define OUT_H 64
#define OUT_W 64

__global__ __launch_bounds__(256) void qpool_kernel(const float* __restrict__ x,
                                                    float* __restrict__ out) {
    // total threads = 16 * 64 * 64 * 32 = 2097152
    // each thread handles 2 adjacent output columns (one float4 of input per row)
    int tid = blockIdx.x * blockDim.x + threadIdx.x;
    int ow2 = tid & 31;          // float4 group: covers ow = 2*ow2, 2*ow2+1
    int oh  = (tid >> 5) & 63;
    int c4i = (tid >> 11) & 63;
    int b   = tid >> 17;

    const long in_ch_stride = (long)IN_H * IN_W;        // 16384
    const long in_b_stride  = 256L * in_ch_stride;
    const float* base = x + (long)b * in_b_stride + (long)c4i * in_ch_stride
                          + (long)(2 * oh) * IN_W + 4 * ow2;

    // arr[q][kh][col]  col in 0..3 (input columns 4*ow2 .. 4*ow2+3)
    float arr[4][2][4];
    #pragma unroll
    for (int q = 0; q < 4; ++q) {
        const float* p = base + (long)q * C4 * in_ch_stride;
        float4 r0 = *(const float4*)(p);
        float4 r1 = *(const float4*)(p + IN_W);
        arr[q][0][0] = r0.x; arr[q][0][1] = r0.y; arr[q][0][2] = r0.z; arr[q][0][3] = r0.w;
        arr[q][1][0] = r1.x; arr[q][1][1] = r1.y; arr[q][1][2] = r1.z; arr[q][1][3] = r1.w;
    }

    float res[4][2];  // [q][slot]
    #pragma unroll
    for (int s = 0; s < 2; ++s) {
        // window columns for this output slot: 2*s + kw
        float amp[4];
        #pragma unroll
        for (int kk = 0; kk < 4; ++kk) {
            const int kh = kk >> 1, kw = kk & 1;
            float sum = 0.f;
            #pragma unroll
            for (int q = 0; q < 4; ++q) {
                float t = arr[q][kh][2 * s + kw];
                sum += t * t;
            }
            amp[kk] = sum;
        }
        // first-occurrence argmax (strict >): matches jnp.argmax
        int best = 0;
        float bv = amp[0];
        #pragma unroll
        for (int kk = 1; kk < 4; ++kk) {
            if (amp[kk] > bv) { bv = amp[kk]; best = kk; }
        }
        #pragma unroll
        for (int q = 0; q < 4; ++q) {
            float r = arr[q][0][2 * s + 0];
            r = (best == 1) ? arr[q][0][2 * s + 1] : r;
            r = (best == 2) ? arr[q][1][2 * s + 0] : r;
            r = (best == 3) ? arr[q][1][2 * s + 1] : r;
            res[q][s] = r;
        }
    }

    const long out_ch_stride = (long)OUT_H * OUT_W;     // 4096
    const long out_b_stride  = 256L * out_ch_stride;
    float* obase = out + (long)b * out_b_stride + (long)c4i * out_ch_stride
                       + (long)oh * OUT_W + 2 * ow2;
    #pragma unroll
    for (int q = 0; q < 4; ++q) {
        float2 w;
        w.x = res[q][0];
        w.y = res[q][1];
        *(float2*)(obase + (long)q * C4 * out_ch_stride) = w;
    }
}

extern "C" void kernel_launch(void* const* d_in, const int* in_sizes, int n_in,
                              void* d_out, int out_size, void* d_ws, size_t ws_size,
                              hipStream_t stream) {
    const float* x = (const float*)d_in[0];
    float* out = (float*)d_out;
    // threads: 16 * 64 * 64 * 32 = 2097152; blocks = 8192
    const int total = 16 * 64 * 64 * 32;
    const int block = 256;
    const int grid = total / block;
    qpool_kernel<<<grid, block, 0, stream>>>(x, out);
}